// Round 2
// baseline (756.843 us; speedup 1.0000x reference)
//
#include <hip/hip_runtime.h>

// PairwiseMLPLinkPredictor on MI355X (gfx950)
// feats = bf16(x[u]) * bf16(x[v]);  h1 = relu(feats@W1+b1);  h2 = relu(h1@W2+b2);
// out = h2@W3 + b3.
//
// R6: role-split wave specialization (from R5 @ 452us, mlp 324us, LDS-issue-bound):
//  - waves 0-7 (P): GEMM1, each owns 64r x 32c -> A-reads halved (512->256 KB/tile)
//  - waves 8-15 (C): GEMM2, each owns 32r x 32c -> A-reads halved (256->128 KB/tile)
//  - each role holds only ITS weight set (64 VGPR) -- fits 128-VGPR cap; residency
//    FORCED via per-iteration asm "+v" (R5's hoist was silently demoted: VGPR=64)
//  - pipelined: GEMM1(t) || GEMM2(t-1) via double-buffered h1 -> ONE barrier/tile
//  - layer-3 part[] reduce deferred one tile (P wave 0 reduces tile t-2) -> no
//    extra barrier; epilogue handles the last tile
//  - staging: all 1024 threads, 2 chunks each, issue at top / consume at end;
//    ep prefetch moved to consume phase to shrink hot-loop register pressure

typedef __attribute__((ext_vector_type(8))) short short8;   // 8 bf16 = 4 VGPRs
typedef __attribute__((ext_vector_type(4))) float floatx4;  // MFMA C/D frag
typedef __attribute__((ext_vector_type(4))) unsigned uintx4;
typedef __attribute__((ext_vector_type(2))) int intx2;

#define MT 64         // pairs per tile
#define NTHREADS 1024 // 16 waves: 8 producer + 8 consumer
#define NBLOCKS 256   // persistent, 1 block/CU (LDS ~130KB)

// force 8 short8 frags to stay register-resident across loop iterations
#define KEEP8(a) asm volatile("" : "+v"(a[0]), "+v"(a[1]), "+v"(a[2]), "+v"(a[3]), \
                                   "+v"(a[4]), "+v"(a[5]), "+v"(a[6]), "+v"(a[7]))

__device__ __forceinline__ unsigned short f2bf(float f) {
  union { float f; unsigned u; } a; a.f = f;
  unsigned r = a.u + 0x7FFFu + ((a.u >> 16) & 1u);   // RNE
  return (unsigned short)(r >> 16);
}

// hw packed f32x2 -> bf16x2 (RNE), lo in low 16
__device__ __forceinline__ unsigned pkbf(float lo, float hi) {
  unsigned r;
  asm("v_cvt_pk_bf16_f32 %0, %1, %2" : "=v"(r) : "v"(lo), "v"(hi));
  return r;
}

// packed bf16x2 multiply via f32 unpack + hw repack
__device__ __forceinline__ unsigned bfmul2(unsigned ua, unsigned ub) {
  float lo = __uint_as_float(ua << 16)          * __uint_as_float(ub << 16);
  float hi = __uint_as_float(ua & 0xFFFF0000u) * __uint_as_float(ub & 0xFFFF0000u);
  return pkbf(lo, hi);
}

// ---------- prologue: x -> bf16 table; W1/W2 -> bf16 transposed [n][k] ----------
__global__ void prep_kernel(const float* __restrict__ x,
                            const float* __restrict__ W1,
                            const float* __restrict__ W2,
                            unsigned short* __restrict__ xb,
                            unsigned short* __restrict__ w1t,
                            unsigned short* __restrict__ w2t, int n4) {
  int i = blockIdx.x * blockDim.x + threadIdx.x;
  if (i < n4) {
    float4 v = ((const float4*)x)[i];
    ushort4 o;
    o.x = f2bf(v.x); o.y = f2bf(v.y); o.z = f2bf(v.z); o.w = f2bf(v.w);
    ((ushort4*)xb)[i] = o;
  } else {
    int j = i - n4;
    if (j < 256 * 256) {
      int k = j >> 8, n = j & 255;
      w1t[n * 256 + k] = f2bf(W1[k * 256 + n]);
    } else {
      j -= 256 * 256;
      if (j < 128 * 256) {
        int k = j >> 7, n = j & 127;
        w2t[n * 256 + k] = f2bf(W2[k * 128 + n]);
      }
    }
  }
}

// ---------- fused pairwise MLP, persistent, role-split P/C waves ----------
__global__ __launch_bounds__(NTHREADS, 4) void mlp_kernel(
    const unsigned short* __restrict__ xb,
    const unsigned short* __restrict__ w1t,
    const unsigned short* __restrict__ w2t,
    const float* __restrict__ b1,
    const float* __restrict__ b2,
    const float* __restrict__ w3,
    const float* __restrict__ b3,
    const int* __restrict__ ep,
    float* __restrict__ out,
    int E)
{
  // 16B chunks XOR-swizzled by (row & 15): conflict-free stride-512 ds_read_b128.
  __shared__ __align__(16) unsigned short feats[2][MT * 256]; // 64 KB
  __shared__ __align__(16) unsigned short h1b[2][MT * 256];   // 64 KB
  __shared__ __align__(16) float part[2][MT][4];              // 2 KB

  const int tid  = threadIdx.x;
  const int wv   = tid >> 6;      // 0..15
  const int lane = tid & 63;
  const int q    = lane >> 4;     // quad 0..3
  const int r16  = lane & 15;
  const int c    = tid & 31;      // 16B chunk within 512B row (staging)
  const int mr0  = tid >> 5;      // staging row base 0..31 (rows mr0, mr0+32)
  const bool isP = (wv < 8);

  const int ntiles = (E + MT - 1) / MT;
  const int b = blockIdx.x;
  const int nloc = (ntiles - 1 - b) / NBLOCKS + 1;  // local tile count (>=2 here)

  // ---- per-role weight registers: 2 col-tiles x 8 k-tiles = 64 VGPR ----
  short8 wA[2][8];
  float bA[2], wS[2];
  if (isP) {
    #pragma unroll
    for (int ct = 0; ct < 2; ++ct) {
      const int n = wv * 32 + ct * 16 + r16;           // col of W1, 0..255
      const unsigned short* p = w1t + n * 256 + q * 8;
      #pragma unroll
      for (int kt = 0; kt < 8; ++kt) wA[ct][kt] = *(const short8*)(p + kt * 32);
      bA[ct] = b1[n];
      wS[ct] = 0.f;
    }
  } else {
    const int cg = (wv - 8) & 3;
    #pragma unroll
    for (int ct = 0; ct < 2; ++ct) {
      const int n = cg * 32 + ct * 16 + r16;           // col of W2, 0..127
      const unsigned short* p = w2t + n * 256 + q * 8;
      #pragma unroll
      for (int kt = 0; kt < 8; ++kt) wA[ct][kt] = *(const short8*)(p + kt * 32);
      bA[ct] = b2[n];
      wS[ct] = w3[n];
    }
  }
  const float b3v = b3[0];

  // ---- prologue: stage tile b into feats[0]; load uv for tile b+NBLOCKS ----
  intx2 uv0, uv1;
  {
    #pragma unroll
    for (int s = 0; s < 2; ++s) {
      int m = mr0 + 32 * s;
      int g = b * MT + m; if (g >= E) g = E - 1;
      intx2 uv = __builtin_nontemporal_load((const intx2*)(ep + 2 * (size_t)g));
      uintx4 a = *(const uintx4*)(xb + ((size_t)(unsigned)uv.x << 8) + (c << 3));
      uintx4 bv = *(const uintx4*)(xb + ((size_t)(unsigned)uv.y << 8) + (c << 3));
      uintx4 pv;
      #pragma unroll
      for (int tt = 0; tt < 4; ++tt) pv[tt] = bfmul2(a[tt], bv[tt]);
      *(uintx4*)((char*)feats[0] + m * 512 + ((c ^ (m & 15)) << 4)) = pv;
    }
    const int t1 = b + NBLOCKS;
    int g0 = t1 * MT + mr0;      if (g0 >= E) g0 = E - 1;
    int g1 = t1 * MT + mr0 + 32; if (g1 >= E) g1 = E - 1;
    uv0 = __builtin_nontemporal_load((const intx2*)(ep + 2 * (size_t)g0));
    uv1 = __builtin_nontemporal_load((const intx2*)(ep + 2 * (size_t)g1));
  }
  __syncthreads();

  for (int i = 0; i <= nloc; ++i) {
    const int fp = i & 1;
    const bool stg = (i + 1 < nloc);   // stage tile i+1 this iteration

    // ---- (1) issue next-tile gather loads (full GEMM-phase latency cover) ----
    uintx4 ra0, rb0, ra1, rb1;
    if (stg) {
      ra0 = *(const uintx4*)(xb + ((size_t)(unsigned)uv0.x << 8) + (c << 3));
      rb0 = *(const uintx4*)(xb + ((size_t)(unsigned)uv0.y << 8) + (c << 3));
      ra1 = *(const uintx4*)(xb + ((size_t)(unsigned)uv1.x << 8) + (c << 3));
      rb1 = *(const uintx4*)(xb + ((size_t)(unsigned)uv1.y << 8) + (c << 3));
    }

    if (isP) {
      // ================= producer: GEMM1 tile i =================
      KEEP8(wA[0]); KEEP8(wA[1]);
      if (i < nloc) {
        floatx4 acc[4][2];
        #pragma unroll
        for (int mt = 0; mt < 4; ++mt) {
          acc[mt][0] = (floatx4){0.f, 0.f, 0.f, 0.f};
          acc[mt][1] = (floatx4){0.f, 0.f, 0.f, 0.f};
        }
        const char* const a1base = (const char*)feats[fp] + r16 * 512;
        #pragma unroll
        for (int kt = 0; kt < 8; ++kt) {
          const int aoff = (kt << 6) ^ ((q ^ r16) << 4);
          #pragma unroll
          for (int mt = 0; mt < 4; ++mt) {
            short8 av = *(const short8*)(a1base + mt * (16 * 512) + aoff);
            acc[mt][0] = __builtin_amdgcn_mfma_f32_16x16x32_bf16(av, wA[0][kt], acc[mt][0], 0, 0, 0);
            acc[mt][1] = __builtin_amdgcn_mfma_f32_16x16x32_bf16(av, wA[1][kt], acc[mt][1], 0, 0, 0);
          }
        }
        // h1 writeback (bias+relu, packed bf16 cvt) into h1b[fp], swizzled
        char* const hb = (char*)h1b[fp];
        #pragma unroll
        for (int ct = 0; ct < 2; ++ct) {
          const int n1  = wv * 32 + ct * 16 + r16;
          const int chb = n1 >> 3;
          const int eo  = (n1 & 7) << 1;
          #pragma unroll
          for (int mt = 0; mt < 4; ++mt) {
            #pragma unroll
            for (int rp = 0; rp < 2; ++rp) {
              float h0 = fmaxf(acc[mt][ct][2 * rp]     + bA[ct], 0.f);
              float h1 = fmaxf(acc[mt][ct][2 * rp + 1] + bA[ct], 0.f);
              unsigned pk = pkbf(h0, h1);
              int m0 = mt * 16 + q * 4 + 2 * rp;
              *(unsigned short*)(hb + m0 * 512 + ((chb ^ (m0 & 15)) << 4) + eo) =
                  (unsigned short)pk;
              *(unsigned short*)(hb + (m0 + 1) * 512 + ((chb ^ ((m0 + 1) & 15)) << 4) + eo) =
                  (unsigned short)(pk >> 16);
            }
          }
        }
      }
      // deferred output reduce: part written at i-1 holds tile i-2
      if (tid < MT && i >= 2) {
        floatx4 pr = *(const floatx4*)part[fp ^ 1][tid];
        out[(b + (i - 2) * NBLOCKS) * MT + tid] =
            (pr[0] + pr[1]) + (pr[2] + pr[3]) + b3v;
      }
    } else {
      // ================= consumer: GEMM2 tile i-1 =================
      KEEP8(wA[0]); KEEP8(wA[1]);
      if (i >= 1) {
        const int cw = wv - 8, mg = cw >> 2, cg = cw & 3;
        floatx4 acc2[2][2];
        acc2[0][0] = (floatx4){0.f, 0.f, 0.f, 0.f};
        acc2[0][1] = (floatx4){0.f, 0.f, 0.f, 0.f};
        acc2[1][0] = (floatx4){0.f, 0.f, 0.f, 0.f};
        acc2[1][1] = (floatx4){0.f, 0.f, 0.f, 0.f};
        const char* const a2base = (const char*)h1b[fp ^ 1] + (mg * 32 + r16) * 512;
        #pragma unroll
        for (int kt = 0; kt < 8; ++kt) {
          const int aoff = (kt << 6) ^ ((q ^ r16) << 4);
          short8 av0 = *(const short8*)(a2base + aoff);
          short8 av1 = *(const short8*)(a2base + 16 * 512 + aoff);
          acc2[0][0] = __builtin_amdgcn_mfma_f32_16x16x32_bf16(av0, wA[0][kt], acc2[0][0], 0, 0, 0);
          acc2[0][1] = __builtin_amdgcn_mfma_f32_16x16x32_bf16(av0, wA[1][kt], acc2[0][1], 0, 0, 0);
          acc2[1][0] = __builtin_amdgcn_mfma_f32_16x16x32_bf16(av1, wA[0][kt], acc2[1][0], 0, 0, 0);
          acc2[1][1] = __builtin_amdgcn_mfma_f32_16x16x32_bf16(av1, wA[1][kt], acc2[1][1], 0, 0, 0);
        }
        // layer 3 partials -> part[fp] (this wave's 32-col contribution)
        #pragma unroll
        for (int mt = 0; mt < 2; ++mt) {
          #pragma unroll
          for (int r = 0; r < 4; ++r) {
            float pp = fmaxf(acc2[mt][0][r] + bA[0], 0.f) * wS[0]
                     + fmaxf(acc2[mt][1][r] + bA[1], 0.f) * wS[1];
            pp += __shfl_xor(pp, 1);
            pp += __shfl_xor(pp, 2);
            pp += __shfl_xor(pp, 4);
            pp += __shfl_xor(pp, 8);
            if (r16 == 0)
              part[fp][mg * 32 + mt * 16 + q * 4 + r][cg] = pp;
          }
        }
      }
    }

    // ---- consume gathers -> feats[fp^1]; prefetch ep for tile i+2 ----
    if (stg) {
      char* const bufn = (char*)feats[fp ^ 1];
      uintx4 pv0, pv1;
      #pragma unroll
      for (int tt = 0; tt < 4; ++tt) pv0[tt] = bfmul2(ra0[tt], rb0[tt]);
      #pragma unroll
      for (int tt = 0; tt < 4; ++tt) pv1[tt] = bfmul2(ra1[tt], rb1[tt]);
      const int m0 = mr0, m1 = mr0 + 32;
      *(uintx4*)(bufn + m0 * 512 + ((c ^ (m0 & 15)) << 4)) = pv0;
      *(uintx4*)(bufn + m1 * 512 + ((c ^ (m1 & 15)) << 4)) = pv1;

      const int t2 = b + (i + 2) * NBLOCKS;
      int g0 = t2 * MT + mr0;      if (g0 >= E) g0 = E - 1;
      int g1 = t2 * MT + mr0 + 32; if (g1 >= E) g1 = E - 1;
      uv0 = __builtin_nontemporal_load((const intx2*)(ep + 2 * (size_t)g0));
      uv1 = __builtin_nontemporal_load((const intx2*)(ep + 2 * (size_t)g1));
    }
    __syncthreads();
  }

  // epilogue: reduce last tile's partials (written at i=nloc into part[nloc&1])
  if (tid < MT) {
    floatx4 pr = *(const floatx4*)part[nloc & 1][tid];
    out[(b + (nloc - 1) * NBLOCKS) * MT + tid] =
        (pr[0] + pr[1]) + (pr[2] + pr[3]) + b3v;
  }
}

extern "C" void kernel_launch(void* const* d_in, const int* in_sizes, int n_in,
                              void* d_out, int out_size, void* d_ws, size_t ws_size,
                              hipStream_t stream) {
  const float* x  = (const float*)d_in[0];
  const float* W1 = (const float*)d_in[1];
  const float* b1 = (const float*)d_in[2];
  const float* W2 = (const float*)d_in[3];
  const float* b2 = (const float*)d_in[4];
  const float* W3 = (const float*)d_in[5];
  const float* b3 = (const float*)d_in[6];
  // d_in[7] = edge_index (unused by the reference computation)
  const int*   ep = (const int*)d_in[8];
  float* out = (float*)d_out;

  const int NX = in_sizes[0];        // 100000*256 = 25,600,000
  const int E  = in_sizes[8] / 2;    // 1,000,000

  // workspace layout: xb (NX bf16) | w1t (256*256 bf16) | w2t (128*256 bf16)
  unsigned short* xb  = (unsigned short*)d_ws;
  unsigned short* w1t = (unsigned short*)((char*)d_ws + (size_t)NX * 2);
  unsigned short* w2t = w1t + 256 * 256;

  const int n4 = NX / 4;
  const int prep_threads = n4 + 256 * 256 + 128 * 256;
  prep_kernel<<<(prep_threads + 255) / 256, 256, 0, stream>>>(x, W1, W2, xb, w1t, w2t, n4);
  mlp_kernel<<<NBLOCKS, NTHREADS, 0, stream>>>(xb, w1t, w2t, b1, b2, W3, b3, ep, out, E);
}

// Round 3
// 583.307 us; speedup vs baseline: 1.2975x; 1.2975x over previous
//
#include <hip/hip_runtime.h>

// PairwiseMLPLinkPredictor on MI355X (gfx950)
// feats = bf16(x[u]) * bf16(x[v]);  h1 = relu(feats@W1+b1);  h2 = relu(h1@W2+b2);
// out = h2@W3 + b3.
//
// R7: fix R6's register catastrophe (R6: VGPR budget stuck at 64 -> 1GB scratch
// spill, 615us; R5 uniform-wave baseline: 324us, LDS-issue-bound):
//  - amdgpu_waves_per_eu(4,4): pin allocator to 4 waves/EU -> 128-VGPR budget
//    (LDS 130KB caps us at 1 block/CU anyway, so this costs zero occupancy)
//  - producer GEMM1 split into two 32-row halves: acc 32->16 VGPR; peak pressure
//    ~112 < 128 for both roles
//  - KEEP8 asm hack REMOVED: under a correct budget, loop-invariant weight loads
//    stay register-resident naturally; under a wrong budget the hack spills (R6)
//  - dataflow identical to R6 (verified correct): 8 P-waves GEMM1 64rx32c,
//    8 C-waves GEMM2 32rx32c, one barrier/tile, deferred out-reduce

typedef __attribute__((ext_vector_type(8))) short short8;   // 8 bf16 = 4 VGPRs
typedef __attribute__((ext_vector_type(4))) float floatx4;  // MFMA C/D frag
typedef __attribute__((ext_vector_type(4))) unsigned uintx4;
typedef __attribute__((ext_vector_type(2))) int intx2;

#define MT 64         // pairs per tile
#define NTHREADS 1024 // 16 waves: 8 producer + 8 consumer
#define NBLOCKS 256   // persistent, 1 block/CU (LDS ~130KB)

__device__ __forceinline__ unsigned short f2bf(float f) {
  union { float f; unsigned u; } a; a.f = f;
  unsigned r = a.u + 0x7FFFu + ((a.u >> 16) & 1u);   // RNE
  return (unsigned short)(r >> 16);
}

// hw packed f32x2 -> bf16x2 (RNE), lo in low 16
__device__ __forceinline__ unsigned pkbf(float lo, float hi) {
  unsigned r;
  asm("v_cvt_pk_bf16_f32 %0, %1, %2" : "=v"(r) : "v"(lo), "v"(hi));
  return r;
}

// packed bf16x2 multiply via f32 unpack + hw repack
__device__ __forceinline__ unsigned bfmul2(unsigned ua, unsigned ub) {
  float lo = __uint_as_float(ua << 16)          * __uint_as_float(ub << 16);
  float hi = __uint_as_float(ua & 0xFFFF0000u) * __uint_as_float(ub & 0xFFFF0000u);
  return pkbf(lo, hi);
}

// ---------- prologue: x -> bf16 table; W1/W2 -> bf16 transposed [n][k] ----------
__global__ void prep_kernel(const float* __restrict__ x,
                            const float* __restrict__ W1,
                            const float* __restrict__ W2,
                            unsigned short* __restrict__ xb,
                            unsigned short* __restrict__ w1t,
                            unsigned short* __restrict__ w2t, int n4) {
  int i = blockIdx.x * blockDim.x + threadIdx.x;
  if (i < n4) {
    float4 v = ((const float4*)x)[i];
    ushort4 o;
    o.x = f2bf(v.x); o.y = f2bf(v.y); o.z = f2bf(v.z); o.w = f2bf(v.w);
    ((ushort4*)xb)[i] = o;
  } else {
    int j = i - n4;
    if (j < 256 * 256) {
      int k = j >> 8, n = j & 255;
      w1t[n * 256 + k] = f2bf(W1[k * 256 + n]);
    } else {
      j -= 256 * 256;
      if (j < 128 * 256) {
        int k = j >> 7, n = j & 127;
        w2t[n * 256 + k] = f2bf(W2[k * 128 + n]);
      }
    }
  }
}

// ---------- fused pairwise MLP, persistent, role-split P/C waves ----------
__global__ __attribute__((amdgpu_waves_per_eu(4, 4))) __launch_bounds__(NTHREADS)
void mlp_kernel(
    const unsigned short* __restrict__ xb,
    const unsigned short* __restrict__ w1t,
    const unsigned short* __restrict__ w2t,
    const float* __restrict__ b1,
    const float* __restrict__ b2,
    const float* __restrict__ w3,
    const float* __restrict__ b3,
    const int* __restrict__ ep,
    float* __restrict__ out,
    int E)
{
  // 16B chunks XOR-swizzled by (row & 15): conflict-free stride-512 ds_read_b128.
  __shared__ __align__(16) unsigned short feats[2][MT * 256]; // 64 KB
  __shared__ __align__(16) unsigned short h1b[2][MT * 256];   // 64 KB
  __shared__ __align__(16) float part[2][MT][4];              // 2 KB

  const int tid  = threadIdx.x;
  const int wv   = tid >> 6;      // 0..15
  const int lane = tid & 63;
  const int q    = lane >> 4;     // quad 0..3
  const int r16  = lane & 15;
  const int c    = tid & 31;      // 16B chunk within 512B row (staging)
  const int mr0  = tid >> 5;      // staging row base 0..31 (rows mr0, mr0+32)
  const bool isP = (wv < 8);

  const int ntiles = (E + MT - 1) / MT;
  const int b = blockIdx.x;
  const int nloc = (ntiles - 1 - b) / NBLOCKS + 1;  // local tile count (>=2 here)

  // ---- per-role weight registers: 2 col-tiles x 8 k-tiles = 64 VGPR ----
  short8 wA[2][8];
  float bA[2], wS[2];
  if (isP) {
    #pragma unroll
    for (int ct = 0; ct < 2; ++ct) {
      const int n = wv * 32 + ct * 16 + r16;           // col of W1, 0..255
      const unsigned short* p = w1t + n * 256 + q * 8;
      #pragma unroll
      for (int kt = 0; kt < 8; ++kt) wA[ct][kt] = *(const short8*)(p + kt * 32);
      bA[ct] = b1[n];
      wS[ct] = 0.f;
    }
  } else {
    const int cg = (wv - 8) & 3;
    #pragma unroll
    for (int ct = 0; ct < 2; ++ct) {
      const int n = cg * 32 + ct * 16 + r16;           // col of W2, 0..127
      const unsigned short* p = w2t + n * 256 + q * 8;
      #pragma unroll
      for (int kt = 0; kt < 8; ++kt) wA[ct][kt] = *(const short8*)(p + kt * 32);
      bA[ct] = b2[n];
      wS[ct] = w3[n];
    }
  }
  const float b3v = b3[0];

  // ---- prologue: stage tile b into feats[0]; load uv for tile b+NBLOCKS ----
  intx2 uv0, uv1;
  {
    #pragma unroll
    for (int s = 0; s < 2; ++s) {
      int m = mr0 + 32 * s;
      int g = b * MT + m; if (g >= E) g = E - 1;
      intx2 uv = __builtin_nontemporal_load((const intx2*)(ep + 2 * (size_t)g));
      uintx4 a = *(const uintx4*)(xb + ((size_t)(unsigned)uv.x << 8) + (c << 3));
      uintx4 bv = *(const uintx4*)(xb + ((size_t)(unsigned)uv.y << 8) + (c << 3));
      uintx4 pv;
      #pragma unroll
      for (int tt = 0; tt < 4; ++tt) pv[tt] = bfmul2(a[tt], bv[tt]);
      *(uintx4*)((char*)feats[0] + m * 512 + ((c ^ (m & 15)) << 4)) = pv;
    }
    const int t1 = b + NBLOCKS;
    int g0 = t1 * MT + mr0;      if (g0 >= E) g0 = E - 1;
    int g1 = t1 * MT + mr0 + 32; if (g1 >= E) g1 = E - 1;
    uv0 = __builtin_nontemporal_load((const intx2*)(ep + 2 * (size_t)g0));
    uv1 = __builtin_nontemporal_load((const intx2*)(ep + 2 * (size_t)g1));
  }
  __syncthreads();

  for (int i = 0; i <= nloc; ++i) {
    const int fp = i & 1;
    const bool stg = (i + 1 < nloc);   // stage tile i+1 this iteration

    // ---- (1) issue next-tile gather loads (full GEMM-phase latency cover) ----
    uintx4 ra0, rb0, ra1, rb1;
    if (stg) {
      ra0 = *(const uintx4*)(xb + ((size_t)(unsigned)uv0.x << 8) + (c << 3));
      rb0 = *(const uintx4*)(xb + ((size_t)(unsigned)uv0.y << 8) + (c << 3));
      ra1 = *(const uintx4*)(xb + ((size_t)(unsigned)uv1.x << 8) + (c << 3));
      rb1 = *(const uintx4*)(xb + ((size_t)(unsigned)uv1.y << 8) + (c << 3));
    }

    if (isP) {
      // ================= producer: GEMM1 tile i (two 32-row halves) =========
      if (i < nloc) {
        char* const hb = (char*)h1b[fp];
        #pragma unroll
        for (int mh = 0; mh < 2; ++mh) {
          floatx4 acc[2][2];
          #pragma unroll
          for (int mt = 0; mt < 2; ++mt) {
            acc[mt][0] = (floatx4){0.f, 0.f, 0.f, 0.f};
            acc[mt][1] = (floatx4){0.f, 0.f, 0.f, 0.f};
          }
          const char* const a1base =
              (const char*)feats[fp] + r16 * 512 + mh * (32 * 512);
          #pragma unroll
          for (int kt = 0; kt < 8; ++kt) {
            const int aoff = (kt << 6) ^ ((q ^ r16) << 4);
            #pragma unroll
            for (int mt = 0; mt < 2; ++mt) {
              short8 av = *(const short8*)(a1base + mt * (16 * 512) + aoff);
              acc[mt][0] = __builtin_amdgcn_mfma_f32_16x16x32_bf16(av, wA[0][kt], acc[mt][0], 0, 0, 0);
              acc[mt][1] = __builtin_amdgcn_mfma_f32_16x16x32_bf16(av, wA[1][kt], acc[mt][1], 0, 0, 0);
            }
          }
          // h1 writeback (bias+relu, packed bf16 cvt) for rows mh*32..mh*32+31
          #pragma unroll
          for (int ct = 0; ct < 2; ++ct) {
            const int n1  = wv * 32 + ct * 16 + r16;
            const int chb = n1 >> 3;
            const int eo  = (n1 & 7) << 1;
            #pragma unroll
            for (int mt = 0; mt < 2; ++mt) {
              #pragma unroll
              for (int rp = 0; rp < 2; ++rp) {
                float h0 = fmaxf(acc[mt][ct][2 * rp]     + bA[ct], 0.f);
                float h1 = fmaxf(acc[mt][ct][2 * rp + 1] + bA[ct], 0.f);
                unsigned pk = pkbf(h0, h1);
                int m0 = mh * 32 + mt * 16 + q * 4 + 2 * rp;
                *(unsigned short*)(hb + m0 * 512 + ((chb ^ (m0 & 15)) << 4) + eo) =
                    (unsigned short)pk;
                *(unsigned short*)(hb + (m0 + 1) * 512 + ((chb ^ ((m0 + 1) & 15)) << 4) + eo) =
                    (unsigned short)(pk >> 16);
              }
            }
          }
        }
      }
      // deferred output reduce: part written at i-1 holds tile i-2
      if (tid < MT && i >= 2) {
        floatx4 pr = *(const floatx4*)part[fp ^ 1][tid];
        out[(b + (i - 2) * NBLOCKS) * MT + tid] =
            (pr[0] + pr[1]) + (pr[2] + pr[3]) + b3v;
      }
    } else {
      // ================= consumer: GEMM2 tile i-1 =================
      if (i >= 1) {
        const int cw = wv - 8, mg = cw >> 2, cg = cw & 3;
        floatx4 acc2[2][2];
        acc2[0][0] = (floatx4){0.f, 0.f, 0.f, 0.f};
        acc2[0][1] = (floatx4){0.f, 0.f, 0.f, 0.f};
        acc2[1][0] = (floatx4){0.f, 0.f, 0.f, 0.f};
        acc2[1][1] = (floatx4){0.f, 0.f, 0.f, 0.f};
        const char* const a2base = (const char*)h1b[fp ^ 1] + (mg * 32 + r16) * 512;
        #pragma unroll
        for (int kt = 0; kt < 8; ++kt) {
          const int aoff = (kt << 6) ^ ((q ^ r16) << 4);
          short8 av0 = *(const short8*)(a2base + aoff);
          short8 av1 = *(const short8*)(a2base + 16 * 512 + aoff);
          acc2[0][0] = __builtin_amdgcn_mfma_f32_16x16x32_bf16(av0, wA[0][kt], acc2[0][0], 0, 0, 0);
          acc2[0][1] = __builtin_amdgcn_mfma_f32_16x16x32_bf16(av0, wA[1][kt], acc2[0][1], 0, 0, 0);
          acc2[1][0] = __builtin_amdgcn_mfma_f32_16x16x32_bf16(av1, wA[0][kt], acc2[1][0], 0, 0, 0);
          acc2[1][1] = __builtin_amdgcn_mfma_f32_16x16x32_bf16(av1, wA[1][kt], acc2[1][1], 0, 0, 0);
        }
        // layer 3 partials -> part[fp] (this wave's 32-col contribution)
        #pragma unroll
        for (int mt = 0; mt < 2; ++mt) {
          #pragma unroll
          for (int r = 0; r < 4; ++r) {
            float pp = fmaxf(acc2[mt][0][r] + bA[0], 0.f) * wS[0]
                     + fmaxf(acc2[mt][1][r] + bA[1], 0.f) * wS[1];
            pp += __shfl_xor(pp, 1);
            pp += __shfl_xor(pp, 2);
            pp += __shfl_xor(pp, 4);
            pp += __shfl_xor(pp, 8);
            if (r16 == 0)
              part[fp][mg * 32 + mt * 16 + q * 4 + r][cg] = pp;
          }
        }
      }
    }

    // ---- consume gathers -> feats[fp^1]; prefetch ep for tile i+2 ----
    if (stg) {
      char* const bufn = (char*)feats[fp ^ 1];
      uintx4 pv0, pv1;
      #pragma unroll
      for (int tt = 0; tt < 4; ++tt) pv0[tt] = bfmul2(ra0[tt], rb0[tt]);
      #pragma unroll
      for (int tt = 0; tt < 4; ++tt) pv1[tt] = bfmul2(ra1[tt], rb1[tt]);
      const int m0 = mr0, m1 = mr0 + 32;
      *(uintx4*)(bufn + m0 * 512 + ((c ^ (m0 & 15)) << 4)) = pv0;
      *(uintx4*)(bufn + m1 * 512 + ((c ^ (m1 & 15)) << 4)) = pv1;

      const int t2 = b + (i + 2) * NBLOCKS;
      int g0 = t2 * MT + mr0;      if (g0 >= E) g0 = E - 1;
      int g1 = t2 * MT + mr0 + 32; if (g1 >= E) g1 = E - 1;
      uv0 = __builtin_nontemporal_load((const intx2*)(ep + 2 * (size_t)g0));
      uv1 = __builtin_nontemporal_load((const intx2*)(ep + 2 * (size_t)g1));
    }
    __syncthreads();
  }

  // epilogue: reduce last tile's partials (written at i=nloc into part[nloc&1])
  if (tid < MT) {
    floatx4 pr = *(const floatx4*)part[nloc & 1][tid];
    out[(b + (nloc - 1) * NBLOCKS) * MT + tid] =
        (pr[0] + pr[1]) + (pr[2] + pr[3]) + b3v;
  }
}

extern "C" void kernel_launch(void* const* d_in, const int* in_sizes, int n_in,
                              void* d_out, int out_size, void* d_ws, size_t ws_size,
                              hipStream_t stream) {
  const float* x  = (const float*)d_in[0];
  const float* W1 = (const float*)d_in[1];
  const float* b1 = (const float*)d_in[2];
  const float* W2 = (const float*)d_in[3];
  const float* b2 = (const float*)d_in[4];
  const float* W3 = (const float*)d_in[5];
  const float* b3 = (const float*)d_in[6];
  // d_in[7] = edge_index (unused by the reference computation)
  const int*   ep = (const int*)d_in[8];
  float* out = (float*)d_out;

  const int NX = in_sizes[0];        // 100000*256 = 25,600,000
  const int E  = in_sizes[8] / 2;    // 1,000,000

  // workspace layout: xb (NX bf16) | w1t (256*256 bf16) | w2t (128*256 bf16)
  unsigned short* xb  = (unsigned short*)d_ws;
  unsigned short* w1t = (unsigned short*)((char*)d_ws + (size_t)NX * 2);
  unsigned short* w2t = w1t + 256 * 256;

  const int n4 = NX / 4;
  const int prep_threads = n4 + 256 * 256 + 128 * 256;
  prep_kernel<<<(prep_threads + 255) / 256, 256, 0, stream>>>(x, W1, W2, xb, w1t, w2t, n4);
  mlp_kernel<<<NBLOCKS, NTHREADS, 0, stream>>>(xb, w1t, w2t, b1, b2, W3, b3, ep, out, E);
}

// Round 4
// 447.980 us; speedup vs baseline: 1.6895x; 1.3021x over previous
//
#include <hip/hip_runtime.h>

// PairwiseMLPLinkPredictor on MI355X (gfx950)
// feats = bf16(x[u]) * bf16(x[v]);  h1 = relu(feats@W1+b1);  h2 = relu(h1@W2+b2);
// out = h2@W3 + b3.
//
// R8: 512-thread blocks to unlock the VGPR budget (R5/R6/R7 evidence: 1024-thr
// workgroups hard-cap at 64 VGPRs on this toolchain -> weights can't be resident).
//  - 8 waves, uniform roles. GEMM1: wave owns 64r x 32c (W1 frags 64 VGPR).
//    GEMM2: wave owns 32r x 32c (W2 frags 64 VGPR). Both resident: b128 LDS
//    traffic/tile 800 -> 416 wave-ops (A1 512->256KB, A2 256->128KB).
//  - h1 writeback packed: v_cvt_pk of the two ct-cols -> single b32 store
//    (16 vs 32 LDS ops/lane). Requires k-permutation of w2t (applied to BOTH
//    MFMA operands -> contraction invariant). Bank-verified 2-way max.
//  - gathers issued AND consumed at iteration top (short live range): at a
//    64-cap worst case this degrades to R5-style remat, not R6-style spill.
//  - 2 barriers/tile; out via part[] + single coalesced store (R5-proven).

typedef __attribute__((ext_vector_type(8))) short short8;   // 8 bf16 = 4 VGPRs
typedef __attribute__((ext_vector_type(4))) float floatx4;  // MFMA C/D frag
typedef __attribute__((ext_vector_type(4))) unsigned uintx4;
typedef __attribute__((ext_vector_type(2))) int intx2;

#define MT 64         // pairs per tile
#define NTHREADS 512  // 8 waves
#define NBLOCKS 256   // persistent, 1 block/CU (LDS ~97KB)

__device__ __forceinline__ unsigned short f2bf(float f) {
  union { float f; unsigned u; } a; a.f = f;
  unsigned r = a.u + 0x7FFFu + ((a.u >> 16) & 1u);   // RNE
  return (unsigned short)(r >> 16);
}

// hw packed f32x2 -> bf16x2 (RNE), lo in low 16
__device__ __forceinline__ unsigned pkbf(float lo, float hi) {
  unsigned r;
  asm("v_cvt_pk_bf16_f32 %0, %1, %2" : "=v"(r) : "v"(lo), "v"(hi));
  return r;
}

// packed bf16x2 multiply via f32 unpack + hw repack
__device__ __forceinline__ unsigned bfmul2(unsigned ua, unsigned ub) {
  float lo = __uint_as_float(ua << 16)          * __uint_as_float(ub << 16);
  float hi = __uint_as_float(ua & 0xFFFF0000u) * __uint_as_float(ub & 0xFFFF0000u);
  return pkbf(lo, hi);
}

// ---------- prologue: x -> bf16 table; W1/W2 -> bf16 transposed [n][k] ----------
// w2t's k-dimension is stored PERMUTED: storage index p holds logical k
// kperm(p) = (p & ~31) | ((p&1)<<4) | ((p&31)>>1), matching the h1 writeback
// packing (lane packs cols n1, n1+16 into adjacent storage slots 2*r16, 2*r16+1).
__global__ void prep_kernel(const float* __restrict__ x,
                            const float* __restrict__ W1,
                            const float* __restrict__ W2,
                            unsigned short* __restrict__ xb,
                            unsigned short* __restrict__ w1t,
                            unsigned short* __restrict__ w2t, int n4) {
  int i = blockIdx.x * blockDim.x + threadIdx.x;
  if (i < n4) {
    float4 v = ((const float4*)x)[i];
    ushort4 o;
    o.x = f2bf(v.x); o.y = f2bf(v.y); o.z = f2bf(v.z); o.w = f2bf(v.w);
    ((ushort4*)xb)[i] = o;
  } else {
    int j = i - n4;
    if (j < 256 * 256) {
      int k = j >> 8, n = j & 255;
      w1t[n * 256 + k] = f2bf(W1[k * 256 + n]);
    } else {
      j -= 256 * 256;
      if (j < 128 * 256) {
        int p = j >> 7, n = j & 127;                       // p = storage k-index
        int kp = (p & ~31) | ((p & 1) << 4) | ((p & 31) >> 1);
        w2t[n * 256 + p] = f2bf(W2[kp * 128 + n]);
      }
    }
  }
}

// ---------- fused pairwise MLP, persistent, 8 waves, weights resident ----------
__global__ __launch_bounds__(NTHREADS, 2) void mlp_kernel(
    const unsigned short* __restrict__ xb,
    const unsigned short* __restrict__ w1t,
    const unsigned short* __restrict__ w2t,
    const float* __restrict__ b1,
    const float* __restrict__ b2,
    const float* __restrict__ w3,
    const float* __restrict__ b3,
    const int* __restrict__ ep,
    float* __restrict__ out,
    int E)
{
  // 16B chunks XOR-swizzled by (row & 15): conflict-free stride-512 ds_read_b128.
  __shared__ __align__(16) unsigned short feats[2][MT * 256]; // 64 KB
  __shared__ __align__(16) unsigned short h1b[MT * 256];      // 32 KB
  __shared__ __align__(16) float part[MT][4];                 // 1 KB

  const int tid  = threadIdx.x;
  const int wv   = tid >> 6;      // 0..7
  const int lane = tid & 63;
  const int q    = lane >> 4;     // quad 0..3
  const int r16  = lane & 15;
  const int c    = tid & 31;      // 16B chunk within 512B row (staging)
  const int mrow = tid >> 5;      // staging row base 0..15 (rows mrow + 16s)
  const int mg   = wv >> 2;       // GEMM2 row slab 0..1
  const int cg   = wv & 3;        // GEMM2 col group 0..3

  const int ntiles = (E + MT - 1) / MT;        // 15625 (E = 64*15625 exactly)
  const int b = blockIdx.x;
  const int nloc = (ntiles - 1 - b) / NBLOCKS + 1;

  // ---- resident weights: W1 2ct x 8kt (64 VGPR) + W2 2ct x 8kt (64 VGPR) ----
  short8 w1r[2][8], w2r[2][8];
  float b1r[2], b2r[2], w3r[2];
  #pragma unroll
  for (int ct = 0; ct < 2; ++ct) {
    const int n1 = wv * 32 + ct * 16 + r16;            // W1 col 0..255
    const unsigned short* p1 = w1t + n1 * 256 + q * 8;
    #pragma unroll
    for (int kt = 0; kt < 8; ++kt) w1r[ct][kt] = *(const short8*)(p1 + kt * 32);
    b1r[ct] = b1[n1];
    const int n2 = cg * 32 + ct * 16 + r16;            // W2 col 0..127
    const unsigned short* p2 = w2t + n2 * 256 + q * 8;
    #pragma unroll
    for (int kt = 0; kt < 8; ++kt) w2r[ct][kt] = *(const short8*)(p2 + kt * 32);
    b2r[ct] = b2[n2];
    w3r[ct] = w3[n2];
  }
  const float b3v = b3[0];

  // ---- prologue: stage tile b into feats[0]; load uv for tile b+NBLOCKS ----
  intx2 uv0, uv1, uv2, uv3;
  {
    #pragma unroll
    for (int s = 0; s < 4; ++s) {
      int m = mrow + 16 * s;
      int g = b * MT + m;                       // < 256*64 << E, no clamp needed
      intx2 uv = __builtin_nontemporal_load((const intx2*)(ep + 2 * (size_t)g));
      uintx4 a  = *(const uintx4*)(xb + ((size_t)(unsigned)uv.x << 8) + (c << 3));
      uintx4 bv = *(const uintx4*)(xb + ((size_t)(unsigned)uv.y << 8) + (c << 3));
      uintx4 pv;
      #pragma unroll
      for (int tt = 0; tt < 4; ++tt) pv[tt] = bfmul2(a[tt], bv[tt]);
      *(uintx4*)((char*)feats[0] + m * 512 + ((c ^ (m & 15)) << 4)) = pv;
    }
    const int t1 = b + NBLOCKS;                 // < 512 < ntiles, no clamp
    uv0 = __builtin_nontemporal_load((const intx2*)(ep + 2 * (size_t)(t1 * MT + mrow)));
    uv1 = __builtin_nontemporal_load((const intx2*)(ep + 2 * (size_t)(t1 * MT + mrow + 16)));
    uv2 = __builtin_nontemporal_load((const intx2*)(ep + 2 * (size_t)(t1 * MT + mrow + 32)));
    uv3 = __builtin_nontemporal_load((const intx2*)(ep + 2 * (size_t)(t1 * MT + mrow + 48)));
  }
  __syncthreads();

  for (int i = 0; i < nloc; ++i) {
    const int fp = i & 1;
    const bool stg = (i + 1 < nloc);

    // ---- (1) stage tile i+1: issue gathers, prefetch ep(i+2), consume now ----
    // Short register live-range: at a 64-VGPR cap this degrades gracefully.
    if (stg) {
      uintx4 ra0 = *(const uintx4*)(xb + ((size_t)(unsigned)uv0.x << 8) + (c << 3));
      uintx4 rb0 = *(const uintx4*)(xb + ((size_t)(unsigned)uv0.y << 8) + (c << 3));
      uintx4 ra1 = *(const uintx4*)(xb + ((size_t)(unsigned)uv1.x << 8) + (c << 3));
      uintx4 rb1 = *(const uintx4*)(xb + ((size_t)(unsigned)uv1.y << 8) + (c << 3));
      uintx4 ra2 = *(const uintx4*)(xb + ((size_t)(unsigned)uv2.x << 8) + (c << 3));
      uintx4 rb2 = *(const uintx4*)(xb + ((size_t)(unsigned)uv2.y << 8) + (c << 3));
      uintx4 ra3 = *(const uintx4*)(xb + ((size_t)(unsigned)uv3.x << 8) + (c << 3));
      uintx4 rb3 = *(const uintx4*)(xb + ((size_t)(unsigned)uv3.y << 8) + (c << 3));

      // ep prefetch for tile i+2 (clamped)
      {
        const int t2 = b + (i + 2) * NBLOCKS;
        int g0 = t2 * MT + mrow;      if (g0 >= E) g0 = E - 1;
        int g1 = t2 * MT + mrow + 16; if (g1 >= E) g1 = E - 1;
        int g2 = t2 * MT + mrow + 32; if (g2 >= E) g2 = E - 1;
        int g3 = t2 * MT + mrow + 48; if (g3 >= E) g3 = E - 1;
        uv0 = __builtin_nontemporal_load((const intx2*)(ep + 2 * (size_t)g0));
        uv1 = __builtin_nontemporal_load((const intx2*)(ep + 2 * (size_t)g1));
        uv2 = __builtin_nontemporal_load((const intx2*)(ep + 2 * (size_t)g2));
        uv3 = __builtin_nontemporal_load((const intx2*)(ep + 2 * (size_t)g3));
      }

      char* const bufn = (char*)feats[fp ^ 1];
      uintx4 pv;
      int m = mrow;
      #pragma unroll
      for (int tt = 0; tt < 4; ++tt) pv[tt] = bfmul2(ra0[tt], rb0[tt]);
      *(uintx4*)(bufn + m * 512 + ((c ^ (m & 15)) << 4)) = pv;
      m = mrow + 16;
      #pragma unroll
      for (int tt = 0; tt < 4; ++tt) pv[tt] = bfmul2(ra1[tt], rb1[tt]);
      *(uintx4*)(bufn + m * 512 + ((c ^ (m & 15)) << 4)) = pv;
      m = mrow + 32;
      #pragma unroll
      for (int tt = 0; tt < 4; ++tt) pv[tt] = bfmul2(ra2[tt], rb2[tt]);
      *(uintx4*)(bufn + m * 512 + ((c ^ (m & 15)) << 4)) = pv;
      m = mrow + 48;
      #pragma unroll
      for (int tt = 0; tt < 4; ++tt) pv[tt] = bfmul2(ra3[tt], rb3[tt]);
      *(uintx4*)(bufn + m * 512 + ((c ^ (m & 15)) << 4)) = pv;
    }

    // ---- (2) GEMM1: feats[fp] x w1r -> 64r x 32c per wave ----
    floatx4 acc[4][2];
    #pragma unroll
    for (int mt = 0; mt < 4; ++mt) {
      acc[mt][0] = (floatx4){0.f, 0.f, 0.f, 0.f};
      acc[mt][1] = (floatx4){0.f, 0.f, 0.f, 0.f};
    }
    const char* const a1base = (const char*)feats[fp] + r16 * 512;
    #pragma unroll
    for (int kt = 0; kt < 8; ++kt) {
      const int aoff = (kt << 6) ^ ((q ^ r16) << 4);
      #pragma unroll
      for (int mt = 0; mt < 4; ++mt) {
        short8 av = *(const short8*)(a1base + mt * (16 * 512) + aoff);
        acc[mt][0] = __builtin_amdgcn_mfma_f32_16x16x32_bf16(av, w1r[0][kt], acc[mt][0], 0, 0, 0);
        acc[mt][1] = __builtin_amdgcn_mfma_f32_16x16x32_bf16(av, w1r[1][kt], acc[mt][1], 0, 0, 0);
      }
    }

    // ---- (3) h1 writeback: pack (ct0,ct1) -> one b32 store per (mt,r) ----
    // storage col p0 = wv*32 + 2*r16 (lo), p0+1 (hi); matches w2t k-perm.
    // addr: row m*512 + swizzled chunk (wv*4 + (r16>>2)) ^ (m&15), +(r16&3)*4.
    {
      char* const hb = (char*)h1b;
      const int chp = wv * 4 + (r16 >> 2);
      const int ino = (r16 & 3) << 2;
      #pragma unroll
      for (int mt = 0; mt < 4; ++mt) {
        #pragma unroll
        for (int r = 0; r < 4; ++r) {
          const int m = mt * 16 + q * 4 + r;
          unsigned pk = pkbf(fmaxf(acc[mt][0][r] + b1r[0], 0.f),
                             fmaxf(acc[mt][1][r] + b1r[1], 0.f));
          *(unsigned*)(hb + m * 512 + ((chp ^ (m & 15)) << 4) + ino) = pk;
        }
      }
    }
    __syncthreads();   // barrier 1: h1 ready; feats[fp^1] staged

    // ---- (4) GEMM2: h1b x w2r -> 32r x 32c per wave (k in permuted order) ----
    floatx4 acc2[2][2];
    acc2[0][0] = (floatx4){0.f, 0.f, 0.f, 0.f};
    acc2[0][1] = (floatx4){0.f, 0.f, 0.f, 0.f};
    acc2[1][0] = (floatx4){0.f, 0.f, 0.f, 0.f};
    acc2[1][1] = (floatx4){0.f, 0.f, 0.f, 0.f};
    const char* const a2base = (const char*)h1b + (mg * 32 + r16) * 512;
    #pragma unroll
    for (int kt = 0; kt < 8; ++kt) {
      const int aoff = (kt << 6) ^ ((q ^ r16) << 4);
      short8 av0 = *(const short8*)(a2base + aoff);
      short8 av1 = *(const short8*)(a2base + 16 * 512 + aoff);
      acc2[0][0] = __builtin_amdgcn_mfma_f32_16x16x32_bf16(av0, w2r[0][kt], acc2[0][0], 0, 0, 0);
      acc2[0][1] = __builtin_amdgcn_mfma_f32_16x16x32_bf16(av0, w2r[1][kt], acc2[0][1], 0, 0, 0);
      acc2[1][0] = __builtin_amdgcn_mfma_f32_16x16x32_bf16(av1, w2r[0][kt], acc2[1][0], 0, 0, 0);
      acc2[1][1] = __builtin_amdgcn_mfma_f32_16x16x32_bf16(av1, w2r[1][kt], acc2[1][1], 0, 0, 0);
    }

    // ---- (5) layer 3 partials: relu(h2)*w3, reduce over r16, part[m][cg] ----
    #pragma unroll
    for (int mt = 0; mt < 2; ++mt) {
      #pragma unroll
      for (int r = 0; r < 4; ++r) {
        float pp = fmaxf(acc2[mt][0][r] + b2r[0], 0.f) * w3r[0]
                 + fmaxf(acc2[mt][1][r] + b2r[1], 0.f) * w3r[1];
        pp += __shfl_xor(pp, 1);
        pp += __shfl_xor(pp, 2);
        pp += __shfl_xor(pp, 4);
        pp += __shfl_xor(pp, 8);
        if (r16 == 0)
          part[mg * 32 + mt * 16 + q * 4 + r][cg] = pp;
      }
    }
    __syncthreads();   // barrier 2: part ready; feats(t+1) visible

    // ---- (6) final reduce + coalesced store ----
    if (tid < MT) {
      floatx4 pr = *(const floatx4*)part[tid];
      out[(size_t)(b + i * NBLOCKS) * MT + tid] =
          (pr[0] + pr[1]) + (pr[2] + pr[3]) + b3v;
    }
  }
}

extern "C" void kernel_launch(void* const* d_in, const int* in_sizes, int n_in,
                              void* d_out, int out_size, void* d_ws, size_t ws_size,
                              hipStream_t stream) {
  const float* x  = (const float*)d_in[0];
  const float* W1 = (const float*)d_in[1];
  const float* b1 = (const float*)d_in[2];
  const float* W2 = (const float*)d_in[3];
  const float* b2 = (const float*)d_in[4];
  const float* W3 = (const float*)d_in[5];
  const float* b3 = (const float*)d_in[6];
  // d_in[7] = edge_index (unused by the reference computation)
  const int*   ep = (const int*)d_in[8];
  float* out = (float*)d_out;

  const int NX = in_sizes[0];        // 100000*256 = 25,600,000
  const int E  = in_sizes[8] / 2;    // 1,000,000

  // workspace layout: xb (NX bf16) | w1t (256*256 bf16) | w2t (128*256 bf16)
  unsigned short* xb  = (unsigned short*)d_ws;
  unsigned short* w1t = (unsigned short*)((char*)d_ws + (size_t)NX * 2);
  unsigned short* w2t = w1t + 256 * 256;

  const int n4 = NX / 4;
  const int prep_threads = n4 + 256 * 256 + 128 * 256;
  prep_kernel<<<(prep_threads + 255) / 256, 256, 0, stream>>>(x, W1, W2, xb, w1t, w2t, n4);
  mlp_kernel<<<NBLOCKS, NTHREADS, 0, stream>>>(xb, w1t, w2t, b1, b2, W3, b3, ep, out, E);
}

// Round 5
// 439.000 us; speedup vs baseline: 1.7240x; 1.0205x over previous
//
#include <hip/hip_runtime.h>

// PairwiseMLPLinkPredictor on MI355X (gfx950)
// feats = bf16(x[u]) * bf16(x[v]);  h1 = relu(feats@W1+b1);  h2 = relu(h1@W2+b2);
// out = h2@W3 + b3.
//
// R9: ONE barrier per tile (from R8 @ 320us: latency-bound, no pipe >30%, 2
// waves/SIMD can't hide phase serialization GEMM1|bar|GEMM2|bar).
//  - h1 double-buffered: GEMM1(t)->h1[fp] and GEMM2(t-1)<-h1[fp^1] are now
//    independent -> single inter-barrier region containing GEMM1, GEMM2,
//    staging(t+1), out-store(t-2): four independent streams for ILP overlap.
//  - part[] double-buffered, out-store deferred 2 tiles (no extra barrier).
//  - __launch_bounds__(512,2): 256-VGPR budget (R8 proved 512thr unlocks the
//    allocator; 1024thr hard-caps at 64). Peak est ~215: weights 128 resident
//    + acc1 16 (GEMM1 in two 32-row halves) + acc2 16 + gather 32 + misc.
//  - LDS 130KB: feats 2x32K + h1 2x32K + part 2x1K. 1 block/CU.
//  - R8's verified pieces kept: w2t k-perm + packed b32 h1 writeback, swizzled
//    conflict-free layouts, part[]+coalesced store, resident weight loads.

typedef __attribute__((ext_vector_type(8))) short short8;   // 8 bf16 = 4 VGPRs
typedef __attribute__((ext_vector_type(4))) float floatx4;  // MFMA C/D frag
typedef __attribute__((ext_vector_type(4))) unsigned uintx4;
typedef __attribute__((ext_vector_type(2))) int intx2;

#define MT 64         // pairs per tile
#define NTHREADS 512  // 8 waves
#define NBLOCKS 256   // persistent, 1 block/CU

__device__ __forceinline__ unsigned short f2bf(float f) {
  union { float f; unsigned u; } a; a.f = f;
  unsigned r = a.u + 0x7FFFu + ((a.u >> 16) & 1u);   // RNE
  return (unsigned short)(r >> 16);
}

// hw packed f32x2 -> bf16x2 (RNE), lo in low 16
__device__ __forceinline__ unsigned pkbf(float lo, float hi) {
  unsigned r;
  asm("v_cvt_pk_bf16_f32 %0, %1, %2" : "=v"(r) : "v"(lo), "v"(hi));
  return r;
}

// packed bf16x2 multiply via f32 unpack + hw repack
__device__ __forceinline__ unsigned bfmul2(unsigned ua, unsigned ub) {
  float lo = __uint_as_float(ua << 16)          * __uint_as_float(ub << 16);
  float hi = __uint_as_float(ua & 0xFFFF0000u) * __uint_as_float(ub & 0xFFFF0000u);
  return pkbf(lo, hi);
}

// ---------- prologue: x -> bf16 table; W1/W2 -> bf16 transposed [n][k] ----------
// w2t's k-dimension is stored PERMUTED: storage index p holds logical k
// kperm(p) = (p & ~31) | ((p&1)<<4) | ((p&31)>>1), matching the h1 writeback
// packing (lane packs cols n1, n1+16 into adjacent storage slots 2*r16, 2*r16+1).
__global__ void prep_kernel(const float* __restrict__ x,
                            const float* __restrict__ W1,
                            const float* __restrict__ W2,
                            unsigned short* __restrict__ xb,
                            unsigned short* __restrict__ w1t,
                            unsigned short* __restrict__ w2t, int n4) {
  int i = blockIdx.x * blockDim.x + threadIdx.x;
  if (i < n4) {
    float4 v = ((const float4*)x)[i];
    ushort4 o;
    o.x = f2bf(v.x); o.y = f2bf(v.y); o.z = f2bf(v.z); o.w = f2bf(v.w);
    ((ushort4*)xb)[i] = o;
  } else {
    int j = i - n4;
    if (j < 256 * 256) {
      int k = j >> 8, n = j & 255;
      w1t[n * 256 + k] = f2bf(W1[k * 256 + n]);
    } else {
      j -= 256 * 256;
      if (j < 128 * 256) {
        int p = j >> 7, n = j & 127;                       // p = storage k-index
        int kp = (p & ~31) | ((p & 1) << 4) | ((p & 31) >> 1);
        w2t[n * 256 + p] = f2bf(W2[kp * 128 + n]);
      }
    }
  }
}

// ---------- fused pairwise MLP, persistent, 8 waves, 1 barrier/tile ----------
__global__ __launch_bounds__(NTHREADS, 2) void mlp_kernel(
    const unsigned short* __restrict__ xb,
    const unsigned short* __restrict__ w1t,
    const unsigned short* __restrict__ w2t,
    const float* __restrict__ b1,
    const float* __restrict__ b2,
    const float* __restrict__ w3,
    const float* __restrict__ b3,
    const int* __restrict__ ep,
    float* __restrict__ out,
    int E)
{
  // 16B chunks XOR-swizzled by (row & 15): conflict-free stride-512 ds_read_b128.
  __shared__ __align__(16) unsigned short feats[2][MT * 256]; // 64 KB
  __shared__ __align__(16) unsigned short h1b[2][MT * 256];   // 64 KB
  __shared__ __align__(16) float part[2][MT][4];              // 2 KB

  const int tid  = threadIdx.x;
  const int wv   = tid >> 6;      // 0..7
  const int lane = tid & 63;
  const int q    = lane >> 4;     // quad 0..3
  const int r16  = lane & 15;
  const int c    = tid & 31;      // 16B chunk within 512B row (staging)
  const int mrow = tid >> 5;      // staging row base 0..15 (rows mrow + 16s)
  const int mg   = wv >> 2;       // GEMM2 row slab 0..1
  const int cg   = wv & 3;        // GEMM2 col group 0..3

  const int ntiles = (E + MT - 1) / MT;        // 15625 (E = 64*15625 exactly)
  const int b = blockIdx.x;
  const int nloc = (ntiles - 1 - b) / NBLOCKS + 1;

  // ---- resident weights: W1 2ct x 8kt (64 VGPR) + W2 2ct x 8kt (64 VGPR) ----
  short8 w1r[2][8], w2r[2][8];
  float b1r[2], b2r[2], w3r[2];
  #pragma unroll
  for (int ct = 0; ct < 2; ++ct) {
    const int n1 = wv * 32 + ct * 16 + r16;            // W1 col 0..255
    const unsigned short* p1 = w1t + n1 * 256 + q * 8;
    #pragma unroll
    for (int kt = 0; kt < 8; ++kt) w1r[ct][kt] = *(const short8*)(p1 + kt * 32);
    b1r[ct] = b1[n1];
    const int n2 = cg * 32 + ct * 16 + r16;            // W2 col 0..127
    const unsigned short* p2 = w2t + n2 * 256 + q * 8;
    #pragma unroll
    for (int kt = 0; kt < 8; ++kt) w2r[ct][kt] = *(const short8*)(p2 + kt * 32);
    b2r[ct] = b2[n2];
    w3r[ct] = w3[n2];
  }
  const float b3v = b3[0];

  // ---- prologue: stage tile b into feats[0]; load uv for tile b+NBLOCKS ----
  intx2 uv0, uv1, uv2, uv3;
  {
    #pragma unroll
    for (int s = 0; s < 4; ++s) {
      int m = mrow + 16 * s;
      int g = b * MT + m;                       // < 256*64 << E, no clamp needed
      intx2 uv = __builtin_nontemporal_load((const intx2*)(ep + 2 * (size_t)g));
      uintx4 a  = *(const uintx4*)(xb + ((size_t)(unsigned)uv.x << 8) + (c << 3));
      uintx4 bv = *(const uintx4*)(xb + ((size_t)(unsigned)uv.y << 8) + (c << 3));
      uintx4 pv;
      #pragma unroll
      for (int tt = 0; tt < 4; ++tt) pv[tt] = bfmul2(a[tt], bv[tt]);
      *(uintx4*)((char*)feats[0] + m * 512 + ((c ^ (m & 15)) << 4)) = pv;
    }
    const int t1 = b + NBLOCKS;                 // < 512 < ntiles, no clamp
    uv0 = __builtin_nontemporal_load((const intx2*)(ep + 2 * (size_t)(t1 * MT + mrow)));
    uv1 = __builtin_nontemporal_load((const intx2*)(ep + 2 * (size_t)(t1 * MT + mrow + 16)));
    uv2 = __builtin_nontemporal_load((const intx2*)(ep + 2 * (size_t)(t1 * MT + mrow + 32)));
    uv3 = __builtin_nontemporal_load((const intx2*)(ep + 2 * (size_t)(t1 * MT + mrow + 48)));
  }
  __syncthreads();

  // iteration i: GEMM1(tile i) | GEMM2(tile i-1) | store(tile i-2) | stage(i+1)
  for (int i = 0; i <= nloc + 1; ++i) {
    const int fp = i & 1;
    const bool stg = (i + 1 < nloc);

    // ---- (1) issue next-tile gathers + ep prefetch (latency covered by GEMMs)
    uintx4 ra0, rb0, ra1, rb1, ra2, rb2, ra3, rb3;
    if (stg) {
      ra0 = *(const uintx4*)(xb + ((size_t)(unsigned)uv0.x << 8) + (c << 3));
      rb0 = *(const uintx4*)(xb + ((size_t)(unsigned)uv0.y << 8) + (c << 3));
      ra1 = *(const uintx4*)(xb + ((size_t)(unsigned)uv1.x << 8) + (c << 3));
      rb1 = *(const uintx4*)(xb + ((size_t)(unsigned)uv1.y << 8) + (c << 3));
      ra2 = *(const uintx4*)(xb + ((size_t)(unsigned)uv2.x << 8) + (c << 3));
      rb2 = *(const uintx4*)(xb + ((size_t)(unsigned)uv2.y << 8) + (c << 3));
      ra3 = *(const uintx4*)(xb + ((size_t)(unsigned)uv3.x << 8) + (c << 3));
      rb3 = *(const uintx4*)(xb + ((size_t)(unsigned)uv3.y << 8) + (c << 3));
    }

    // ---- (2) GEMM1 tile i: feats[fp] x w1r, two 32-row halves; h1 -> h1b[fp]
    if (i < nloc) {
      char* const hb = (char*)h1b[fp];
      const int chp = wv * 4 + (r16 >> 2);
      const int ino = (r16 & 3) << 2;
      #pragma unroll
      for (int mh = 0; mh < 2; ++mh) {
        floatx4 acc[2][2];
        #pragma unroll
        for (int mt = 0; mt < 2; ++mt) {
          acc[mt][0] = (floatx4){0.f, 0.f, 0.f, 0.f};
          acc[mt][1] = (floatx4){0.f, 0.f, 0.f, 0.f};
        }
        const char* const a1base =
            (const char*)feats[fp] + r16 * 512 + mh * (32 * 512);
        #pragma unroll
        for (int kt = 0; kt < 8; ++kt) {
          const int aoff = (kt << 6) ^ ((q ^ r16) << 4);
          #pragma unroll
          for (int mt = 0; mt < 2; ++mt) {
            short8 av = *(const short8*)(a1base + mt * (16 * 512) + aoff);
            acc[mt][0] = __builtin_amdgcn_mfma_f32_16x16x32_bf16(av, w1r[0][kt], acc[mt][0], 0, 0, 0);
            acc[mt][1] = __builtin_amdgcn_mfma_f32_16x16x32_bf16(av, w1r[1][kt], acc[mt][1], 0, 0, 0);
          }
        }
        // h1 writeback: pack (ct0,ct1) -> one b32 store per (mt,r)
        #pragma unroll
        for (int mt = 0; mt < 2; ++mt) {
          #pragma unroll
          for (int r = 0; r < 4; ++r) {
            const int m = mh * 32 + mt * 16 + q * 4 + r;
            unsigned pk = pkbf(fmaxf(acc[mt][0][r] + b1r[0], 0.f),
                               fmaxf(acc[mt][1][r] + b1r[1], 0.f));
            *(unsigned*)(hb + m * 512 + ((chp ^ (m & 15)) << 4) + ino) = pk;
          }
        }
      }
    }

    // ---- (3) consume gathers -> feats[fp^1]; prefetch ep for tile i+2 ----
    if (stg) {
      char* const bufn = (char*)feats[fp ^ 1];
      uintx4 pv;
      int m = mrow;
      #pragma unroll
      for (int tt = 0; tt < 4; ++tt) pv[tt] = bfmul2(ra0[tt], rb0[tt]);
      *(uintx4*)(bufn + m * 512 + ((c ^ (m & 15)) << 4)) = pv;
      m = mrow + 16;
      #pragma unroll
      for (int tt = 0; tt < 4; ++tt) pv[tt] = bfmul2(ra1[tt], rb1[tt]);
      *(uintx4*)(bufn + m * 512 + ((c ^ (m & 15)) << 4)) = pv;
      m = mrow + 32;
      #pragma unroll
      for (int tt = 0; tt < 4; ++tt) pv[tt] = bfmul2(ra2[tt], rb2[tt]);
      *(uintx4*)(bufn + m * 512 + ((c ^ (m & 15)) << 4)) = pv;
      m = mrow + 48;
      #pragma unroll
      for (int tt = 0; tt < 4; ++tt) pv[tt] = bfmul2(ra3[tt], rb3[tt]);
      *(uintx4*)(bufn + m * 512 + ((c ^ (m & 15)) << 4)) = pv;

      const int t2 = b + (i + 2) * NBLOCKS;
      int g0 = t2 * MT + mrow;      if (g0 >= E) g0 = E - 1;
      int g1 = t2 * MT + mrow + 16; if (g1 >= E) g1 = E - 1;
      int g2 = t2 * MT + mrow + 32; if (g2 >= E) g2 = E - 1;
      int g3 = t2 * MT + mrow + 48; if (g3 >= E) g3 = E - 1;
      uv0 = __builtin_nontemporal_load((const intx2*)(ep + 2 * (size_t)g0));
      uv1 = __builtin_nontemporal_load((const intx2*)(ep + 2 * (size_t)g1));
      uv2 = __builtin_nontemporal_load((const intx2*)(ep + 2 * (size_t)g2));
      uv3 = __builtin_nontemporal_load((const intx2*)(ep + 2 * (size_t)g3));
    }

    // ---- (4) GEMM2 tile i-1: h1b[fp^1] x w2r (k in permuted order) ----
    if (i >= 1 && i <= nloc) {
      floatx4 acc2[2][2];
      acc2[0][0] = (floatx4){0.f, 0.f, 0.f, 0.f};
      acc2[0][1] = (floatx4){0.f, 0.f, 0.f, 0.f};
      acc2[1][0] = (floatx4){0.f, 0.f, 0.f, 0.f};
      acc2[1][1] = (floatx4){0.f, 0.f, 0.f, 0.f};
      const char* const a2base =
          (const char*)h1b[fp ^ 1] + (mg * 32 + r16) * 512;
      #pragma unroll
      for (int kt = 0; kt < 8; ++kt) {
        const int aoff = (kt << 6) ^ ((q ^ r16) << 4);
        short8 av0 = *(const short8*)(a2base + aoff);
        short8 av1 = *(const short8*)(a2base + 16 * 512 + aoff);
        acc2[0][0] = __builtin_amdgcn_mfma_f32_16x16x32_bf16(av0, w2r[0][kt], acc2[0][0], 0, 0, 0);
        acc2[0][1] = __builtin_amdgcn_mfma_f32_16x16x32_bf16(av0, w2r[1][kt], acc2[0][1], 0, 0, 0);
        acc2[1][0] = __builtin_amdgcn_mfma_f32_16x16x32_bf16(av1, w2r[0][kt], acc2[1][0], 0, 0, 0);
        acc2[1][1] = __builtin_amdgcn_mfma_f32_16x16x32_bf16(av1, w2r[1][kt], acc2[1][1], 0, 0, 0);
      }
      // layer 3 partials -> part[fp^1] ( = (i-1)&1 )
      #pragma unroll
      for (int mt = 0; mt < 2; ++mt) {
        #pragma unroll
        for (int r = 0; r < 4; ++r) {
          float pp = fmaxf(acc2[mt][0][r] + b2r[0], 0.f) * w3r[0]
                   + fmaxf(acc2[mt][1][r] + b2r[1], 0.f) * w3r[1];
          pp += __shfl_xor(pp, 1);
          pp += __shfl_xor(pp, 2);
          pp += __shfl_xor(pp, 4);
          pp += __shfl_xor(pp, 8);
          if (r16 == 0)
            part[fp ^ 1][mg * 32 + mt * 16 + q * 4 + r][cg] = pp;
        }
      }
    }

    // ---- (5) store tile i-2 from part[fp] (written last iteration) ----
    if (i >= 2 && tid < MT) {
      floatx4 pr = *(const floatx4*)part[fp][tid];
      out[(size_t)(b + (i - 2) * NBLOCKS) * MT + tid] =
          (pr[0] + pr[1]) + (pr[2] + pr[3]) + b3v;
    }

    __syncthreads();   // the ONLY barrier: flips all double-buffers
  }
}

extern "C" void kernel_launch(void* const* d_in, const int* in_sizes, int n_in,
                              void* d_out, int out_size, void* d_ws, size_t ws_size,
                              hipStream_t stream) {
  const float* x  = (const float*)d_in[0];
  const float* W1 = (const float*)d_in[1];
  const float* b1 = (const float*)d_in[2];
  const float* W2 = (const float*)d_in[3];
  const float* b2 = (const float*)d_in[4];
  const float* W3 = (const float*)d_in[5];
  const float* b3 = (const float*)d_in[6];
  // d_in[7] = edge_index (unused by the reference computation)
  const int*   ep = (const int*)d_in[8];
  float* out = (float*)d_out;

  const int NX = in_sizes[0];        // 100000*256 = 25,600,000
  const int E  = in_sizes[8] / 2;    // 1,000,000

  // workspace layout: xb (NX bf16) | w1t (256*256 bf16) | w2t (128*256 bf16)
  unsigned short* xb  = (unsigned short*)d_ws;
  unsigned short* w1t = (unsigned short*)((char*)d_ws + (size_t)NX * 2);
  unsigned short* w2t = w1t + 256 * 256;

  const int n4 = NX / 4;
  const int prep_threads = n4 + 256 * 256 + 128 * 256;
  prep_kernel<<<(prep_threads + 255) / 256, 256, 0, stream>>>(x, W1, W2, xb, w1t, w2t, n4);
  mlp_kernel<<<NBLOCKS, NTHREADS, 0, stream>>>(xb, w1t, w2t, b1, b2, W3, b3, ep, out, E);
}